// Round 8
// baseline (369.112 us; speedup 1.0000x reference)
//
#include <hip/hip_runtime.h>
#include <hip/hip_bf16.h>

#define VOCAB 256
#define EMB   32
#define HID   128
#define GATES 512
#define BATCH 512
#define SEQ   512
#define HSTRIDE 144   // shorts; 288 B = 8-bank row offset -> uniform 2-way (free)

#define LOG2E 1.442695041f
#if __has_builtin(__builtin_amdgcn_exp2f)
#define GEXP(x) __builtin_amdgcn_exp2f(x)
#define SCALE_IFO LOG2E
#define SCALE_G   (2.0f * LOG2E)
#else
#define GEXP(x) __expf(x)
#define SCALE_IFO 1.0f
#define SCALE_G   2.0f
#endif

typedef __attribute__((ext_vector_type(8))) short bf16x8;
typedef __attribute__((ext_vector_type(4))) float f32x4;

static __device__ __forceinline__ unsigned short f2bf(float f) {
  unsigned int u = __float_as_uint(f);
  return (unsigned short)((u + 0x7fffu + ((u >> 16) & 1u)) >> 16);
}

// ws layout: P[VOCAB][GATES] f32 (512 KB) | Whh_bf16[GATES][HID] (128 KB)
// Both P and W_hh are PRESCALED per gate type: i,f,o by SCALE_IFO, g by SCALE_G,
// so gate math uses raw 2^x (v_exp) with no per-use multiply.
__global__ __launch_bounds__(256) void prep_kernel(
    const float* __restrict__ emb, const float* __restrict__ W_ih,
    const float* __restrict__ W_hh, const float* __restrict__ b_ih,
    const float* __restrict__ b_hh, float* __restrict__ P,
    unsigned short* __restrict__ Whh_bf) {
  const int wg  = blockIdx.x;
  const int tid = threadIdx.x;
  if (wg < VOCAB) {
    __shared__ float e[EMB];
    if (tid < EMB) e[tid] = emb[wg * EMB + tid];
    __syncthreads();
    for (int g = tid; g < GATES; g += 256) {
      float acc = b_ih[g] + b_hh[g];
      const float* w = W_ih + g * EMB;
      #pragma unroll
      for (int k = 0; k < EMB; ++k) acc += e[k] * w[k];
      const float sc = ((g >> 7) == 2) ? SCALE_G : SCALE_IFO;
      P[wg * GATES + g] = acc * sc;
    }
  } else {
    const int base = (wg - VOCAB) * 1024 + tid * 4;   // flat idx into [512][128]
    const float sc = (((base >> 14) & 3) == 2) ? SCALE_G : SCALE_IFO;
    const float4 v = *(const float4*)(W_hh + base);
    ushort4 o;
    o.x = f2bf(v.x * sc); o.y = f2bf(v.y * sc);
    o.z = f2bf(v.z * sc); o.w = f2bf(v.w * sc);
    *(ushort4*)(Whh_bf + base) = o;
  }
}

// 128 WGs x 512 threads (8 waves = 2/SIMD). WG owns batch rows b0..b0+3.
// wave w owns j in [16w,16w+16) for all 4 gate types.
// A row m = h[m&3] => acc reg r = batch row r for every lane.
// Lane (c16,kg) owns output (row=kg, j=16w+c16)  [bijective, 512 lanes].
// VALU diet: P enters as the MFMA C operand (no acc zeroing, no post-add);
// per-step P addresses come from a precomputed offs[] LDS table (1 ds_read_b128
// + 4 adds + 16 imm-offset loads, prefetched one full step ahead); loop is
// unrolled x2 so both h-buffers have compile-time LDS addresses.
__global__ __launch_bounds__(512, 2) void lstm_kernel(
    const int* __restrict__ inputs, const float* __restrict__ P,
    const unsigned short* __restrict__ Whh_bf,
    const float* __restrict__ W_cls, const float* __restrict__ b_cls,
    float* __restrict__ out) {
  const int wg   = blockIdx.x;
  const int tid  = threadIdx.x;
  const int wave = tid >> 6;          // 0..7
  const int lane = tid & 63;
  const int c16  = lane & 15;
  const int kg   = lane >> 4;         // 0..3
  const int b0   = wg * 4;

  const int row   = kg;                        // this lane's batch row (0..3)
  const int jfull = wave * 16 + c16;           // 0..127 hidden index

  __shared__ unsigned int   offs[SEQ][4];          // 8 KB: ch*512 element offsets
  __shared__ unsigned short hbufA[4 * HSTRIDE];    // even steps: read A, write B
  __shared__ unsigned short hbufB[4 * HSTRIDE];
  __shared__ float          h_last[4][HID];        // 2 KB

  for (int k = tid; k < 4 * SEQ; k += 512) {
    const int r = k & 3, t = k >> 2;
    offs[t][r] = ((unsigned int)(inputs[(b0 + r) * SEQ + t] & 0xff)) << 9;
  }
  for (int k = tid; k < 4 * HSTRIDE; k += 512) { hbufA[k] = 0; hbufB[k] = 0; }

  // B-frags resident (prescaled): Bfrag[gt][ks] lane (c16,kg) =
  //   W_hh[gt*128+16w+c16][ks*32+kg*8..+7] * scale(gt)
  bf16x8 Bfrag[4][4];
  #pragma unroll
  for (int gt = 0; gt < 4; ++gt) {
    const int g = gt * 128 + wave * 16 + c16;
    #pragma unroll
    for (int ks = 0; ks < 4; ++ks)
      Bfrag[gt][ks] = *(const bf16x8*)(Whh_bf + g * HID + ks * 32 + kg * 8);
  }

  const int aoff = (c16 & 3) * HSTRIDE + kg * 8;   // A-frag: h[c16&3][kg*8..]
  float cstate = 0.f;
  float hv = 0.f;

  __syncthreads();

  // step-0 P values (C-in for the first MFMA)
  f32x4 pcur[4];
  {
    const uint4 o4 = *(const uint4*)&offs[0][0];
    const float* r0 = P + o4.x + jfull;
    const float* r1 = P + o4.y + jfull;
    const float* r2 = P + o4.z + jfull;
    const float* r3 = P + o4.w + jfull;
    #pragma unroll
    for (int gt = 0; gt < 4; ++gt) {
      pcur[gt][0] = r0[gt * 128]; pcur[gt][1] = r1[gt * 128];
      pcur[gt][2] = r2[gt * 128]; pcur[gt][3] = r3[gt * 128];
    }
  }

#define STEP(HIN, HOUT, T)                                                     \
  {                                                                            \
    /* prefetch next step's P (consumed after next barrier) */                 \
    const uint4 o4 = *(const uint4*)&offs[((T) + 1) & (SEQ - 1)][0];           \
    f32x4 pn0, pn1, pn2, pn3;                                                  \
    {                                                                          \
      const float* r0 = P + o4.x + jfull;                                      \
      const float* r1 = P + o4.y + jfull;                                      \
      const float* r2 = P + o4.z + jfull;                                      \
      const float* r3 = P + o4.w + jfull;                                      \
      pn0[0] = r0[0];   pn0[1] = r1[0];   pn0[2] = r2[0];   pn0[3] = r3[0];    \
      pn1[0] = r0[128]; pn1[1] = r1[128]; pn1[2] = r2[128]; pn1[3] = r3[128];  \
      pn2[0] = r0[256]; pn2[1] = r1[256]; pn2[2] = r2[256]; pn2[3] = r3[256];  \
      pn3[0] = r0[384]; pn3[1] = r1[384]; pn3[2] = r2[384]; pn3[3] = r3[384];  \
    }                                                                          \
    const unsigned short* hb = (HIN) + aoff;                                   \
    const bf16x8 A0 = *(const bf16x8*)(hb);                                    \
    const bf16x8 A1 = *(const bf16x8*)(hb + 32);                               \
    const bf16x8 A2 = *(const bf16x8*)(hb + 64);                               \
    const bf16x8 A3 = *(const bf16x8*)(hb + 96);                               \
    f32x4 a0 = pcur[0], a1 = pcur[1], a2 = pcur[2], a3 = pcur[3];              \
    a0 = __builtin_amdgcn_mfma_f32_16x16x32_bf16(A0, Bfrag[0][0], a0, 0,0,0);  \
    a1 = __builtin_amdgcn_mfma_f32_16x16x32_bf16(A0, Bfrag[1][0], a1, 0,0,0);  \
    a2 = __builtin_amdgcn_mfma_f32_16x16x32_bf16(A0, Bfrag[2][0], a2, 0,0,0);  \
    a3 = __builtin_amdgcn_mfma_f32_16x16x32_bf16(A0, Bfrag[3][0], a3, 0,0,0);  \
    a0 = __builtin_amdgcn_mfma_f32_16x16x32_bf16(A1, Bfrag[0][1], a0, 0,0,0);  \
    a1 = __builtin_amdgcn_mfma_f32_16x16x32_bf16(A1, Bfrag[1][1], a1, 0,0,0);  \
    a2 = __builtin_amdgcn_mfma_f32_16x16x32_bf16(A1, Bfrag[2][1], a2, 0,0,0);  \
    a3 = __builtin_amdgcn_mfma_f32_16x16x32_bf16(A1, Bfrag[3][1], a3, 0,0,0);  \
    a0 = __builtin_amdgcn_mfma_f32_16x16x32_bf16(A2, Bfrag[0][2], a0, 0,0,0);  \
    a1 = __builtin_amdgcn_mfma_f32_16x16x32_bf16(A2, Bfrag[1][2], a1, 0,0,0);  \
    a2 = __builtin_amdgcn_mfma_f32_16x16x32_bf16(A2, Bfrag[2][2], a2, 0,0,0);  \
    a3 = __builtin_amdgcn_mfma_f32_16x16x32_bf16(A2, Bfrag[3][2], a3, 0,0,0);  \
    a0 = __builtin_amdgcn_mfma_f32_16x16x32_bf16(A3, Bfrag[0][3], a0, 0,0,0);  \
    a1 = __builtin_amdgcn_mfma_f32_16x16x32_bf16(A3, Bfrag[1][3], a1, 0,0,0);  \
    a2 = __builtin_amdgcn_mfma_f32_16x16x32_bf16(A3, Bfrag[2][3], a2, 0,0,0);  \
    a3 = __builtin_amdgcn_mfma_f32_16x16x32_bf16(A3, Bfrag[3][3], a3, 0,0,0);  \
    const float gi = (kg & 2) ? ((kg & 1) ? a0[3] : a0[2])                     \
                              : ((kg & 1) ? a0[1] : a0[0]);                    \
    const float gf = (kg & 2) ? ((kg & 1) ? a1[3] : a1[2])                     \
                              : ((kg & 1) ? a1[1] : a1[0]);                    \
    const float gg = (kg & 2) ? ((kg & 1) ? a2[3] : a2[2])                     \
                              : ((kg & 1) ? a2[1] : a2[0]);                    \
    const float go = (kg & 2) ? ((kg & 1) ? a3[3] : a3[2])                     \
                              : ((kg & 1) ? a3[1] : a3[0]);                    \
    const float iv = __builtin_amdgcn_rcpf(1.f + GEXP(-gi));                   \
    const float fv = __builtin_amdgcn_rcpf(1.f + GEXP(-gf));                   \
    const float gv = 1.f - 2.f * __builtin_amdgcn_rcpf(GEXP(gg) + 1.f);        \
    const float ov = __builtin_amdgcn_rcpf(1.f + GEXP(-go));                   \
    cstate = fv * cstate + iv * gv;                                            \
    const float th =                                                           \
        1.f - 2.f * __builtin_amdgcn_rcpf(GEXP(cstate * SCALE_G) + 1.f);       \
    hv = ov * th;                                                              \
    (HOUT)[row * HSTRIDE + jfull] = f2bf(hv);                                  \
    pcur[0] = pn0; pcur[1] = pn1; pcur[2] = pn2; pcur[3] = pn3;                \
    __syncthreads();                                                           \
  }

  #pragma unroll 1
  for (int t = 0; t < SEQ; t += 2) {
    STEP(hbufA, hbufB, t)
    STEP(hbufB, hbufA, t + 1)
  }
#undef STEP

  // final h written once
  h_last[row][jfull] = hv;
  __syncthreads();

  // classifier: 4 rows x 256 vocab = 1024 outputs, 2 per thread
  const int erow = tid >> 7;          // 0..3
  const int ej   = tid & 127;
  #pragma unroll
  for (int half = 0; half < 2; ++half) {
    const int v = ej + half * 128;
    float acc = b_cls[v];
    const float4* w  = (const float4*)(W_cls + v * HID);
    const float4* hh = (const float4*)&h_last[erow][0];
    #pragma unroll
    for (int k = 0; k < HID / 4; ++k) {
      const float4 wv = w[k];
      const float4 hv4 = hh[k];
      acc += wv.x * hv4.x + wv.y * hv4.y + wv.z * hv4.z + wv.w * hv4.w;
    }
    out[(b0 + erow) * VOCAB + v] = acc;
  }
}

extern "C" void kernel_launch(void* const* d_in, const int* in_sizes, int n_in,
                              void* d_out, int out_size, void* d_ws, size_t ws_size,
                              hipStream_t stream) {
  const int*   inputs = (const int*)d_in[0];
  const float* emb    = (const float*)d_in[1];
  const float* W_ih   = (const float*)d_in[2];
  const float* W_hh   = (const float*)d_in[3];
  const float* b_ih   = (const float*)d_in[4];
  const float* b_hh   = (const float*)d_in[5];
  const float* W_cls  = (const float*)d_in[6];
  const float* b_cls  = (const float*)d_in[7];
  float* outp = (float*)d_out;

  float* Ptab = (float*)d_ws;
  unsigned short* Whh_bf = (unsigned short*)((char*)d_ws + VOCAB * GATES * sizeof(float));

  prep_kernel<<<VOCAB + 64, 256, 0, stream>>>(emb, W_ih, W_hh, b_ih, b_hh, Ptab, Whh_bf);
  lstm_kernel<<<BATCH / 4, 512, 0, stream>>>(inputs, Ptab, Whh_bf, W_cls, b_cls, outp);
}

// Round 9
// 314.406 us; speedup vs baseline: 1.1740x; 1.1740x over previous
//
#include <hip/hip_runtime.h>
#include <hip/hip_bf16.h>

#define VOCAB 256
#define EMB   32
#define HID   128
#define GATES 512
#define BATCH 512
#define SEQ   512
#define HSTRIDE 144   // shorts; 288 B row stride -> uniform 2-way LDS access (free)

#define LOG2E 1.442695041f
#if __has_builtin(__builtin_amdgcn_exp2f)
#define GEXP(x) __builtin_amdgcn_exp2f(x)
#define SCALE_IFO LOG2E
#define SCALE_G   (2.0f * LOG2E)
#else
#define GEXP(x) __expf(x)
#define SCALE_IFO 1.0f
#define SCALE_G   2.0f
#endif

typedef __attribute__((ext_vector_type(8))) short bf16x8;
typedef __attribute__((ext_vector_type(4))) float f32x4;

static __device__ __forceinline__ unsigned short f2bf(float f) {
  unsigned int u = __float_as_uint(f);
  return (unsigned short)((u + 0x7fffu + ((u >> 16) & 1u)) >> 16);
}

// ws layout: P[VOCAB][GATES] f32 (512 KB), PRESCALED per gate type
// (i,f,o by SCALE_IFO; g by SCALE_G) so gate math uses raw 2^x.
__global__ __launch_bounds__(256) void prep_kernel(
    const float* __restrict__ emb, const float* __restrict__ W_ih,
    const float* __restrict__ b_ih, const float* __restrict__ b_hh,
    float* __restrict__ P) {
  const int wg  = blockIdx.x;
  const int tid = threadIdx.x;
  __shared__ float e[EMB];
  if (tid < EMB) e[tid] = emb[wg * EMB + tid];
  __syncthreads();
  for (int g = tid; g < GATES; g += 256) {
    float acc = b_ih[g] + b_hh[g];
    const float* w = W_ih + g * EMB;
    #pragma unroll
    for (int k = 0; k < EMB; ++k) acc += e[k] * w[k];
    const float sc = ((g >> 7) == 2) ? SCALE_G : SCALE_IFO;
    P[wg * GATES + g] = acc * sc;
  }
}

// 128 WGs x 512 threads (8 waves = 2/SIMD). WG owns batch rows b0..b0+3.
// wave w owns j in [16w,16w+16) for all 4 gate types (4 n-tiles x 4 ks).
// A row m = h[m&3] => acc reg r = batch row r for every lane.
// Lane (c16,kg) owns output (row=kg, j=16w+c16)  [bijective, 512 lanes].
// One barrier/step; next-step P prefetch (4 loads/lane, no redundancy);
// W_hh converted to prescaled bf16 in-register at init (no prep pass).
__global__ __launch_bounds__(512, 2) void lstm_kernel(
    const int* __restrict__ inputs, const float* __restrict__ P,
    const float* __restrict__ W_hh,
    const float* __restrict__ W_cls, const float* __restrict__ b_cls,
    float* __restrict__ out) {
  const int wg   = blockIdx.x;
  const int tid  = threadIdx.x;
  const int wave = tid >> 6;          // 0..7
  const int lane = tid & 63;
  const int c16  = lane & 15;
  const int kg   = lane >> 4;         // 0..3
  const int b0   = wg * 4;

  const int row   = kg;                        // this lane's batch row (0..3)
  const int jfull = wave * 16 + c16;           // 0..127 hidden index

  __shared__ unsigned char  chars[4][SEQ];        // 2 KB
  __shared__ unsigned short hbufA[4 * HSTRIDE];   // even steps read A, write B
  __shared__ unsigned short hbufB[4 * HSTRIDE];
  __shared__ float          h_last[4][HID];       // 2 KB

  for (int k = tid; k < 4 * SEQ; k += 512) {
    const int r = k >> 9, t = k & (SEQ - 1);
    chars[r][t] = (unsigned char)(inputs[(b0 + r) * SEQ + t] & 0xff);
  }
  for (int k = tid; k < 4 * HSTRIDE; k += 512) { hbufA[k] = 0; hbufB[k] = 0; }

  // B-frags: convert W_hh f32 -> prescaled bf16 in-register (one-time; L2-served)
  // Bfrag[gt][ks] lane (c16,kg) = W_hh[gt*128+16w+c16][ks*32+kg*8..+7] * scale(gt)
  bf16x8 Bfrag[4][4];
  #pragma unroll
  for (int gt = 0; gt < 4; ++gt) {
    const float sc = (gt == 2) ? SCALE_G : SCALE_IFO;
    const float* wr = W_hh + (gt * 128 + wave * 16 + c16) * HID + kg * 8;
    #pragma unroll
    for (int ks = 0; ks < 4; ++ks) {
      const float4 w0 = *(const float4*)(wr + ks * 32);
      const float4 w1 = *(const float4*)(wr + ks * 32 + 4);
      bf16x8 b;
      b[0] = (short)f2bf(w0.x * sc); b[1] = (short)f2bf(w0.y * sc);
      b[2] = (short)f2bf(w0.z * sc); b[3] = (short)f2bf(w0.w * sc);
      b[4] = (short)f2bf(w1.x * sc); b[5] = (short)f2bf(w1.y * sc);
      b[6] = (short)f2bf(w1.z * sc); b[7] = (short)f2bf(w1.w * sc);
      Bfrag[gt][ks] = b;
    }
  }

  const int aoff = (c16 & 3) * HSTRIDE + kg * 8;   // A-frag: h[c16&3][kg*8..]
  const float* Pj = P + jfull;
  float cstate = 0.f;
  float hv = 0.f;

  __syncthreads();

  // step-0 P values
  const float* Pr0 = Pj + ((size_t)chars[row][0] << 9);
  float p0 = Pr0[0], p1 = Pr0[128], p2 = Pr0[256], p3 = Pr0[384];

#define STEP(HIN, HOUT, T)                                                     \
  {                                                                            \
    /* prefetch next step's P (4 loads/lane; consumed next iteration) */       \
    const int chn = chars[row][((T) + 1) & (SEQ - 1)];                         \
    const float* Pn = Pj + ((size_t)chn << 9);                                 \
    const float q0 = Pn[0], q1 = Pn[128], q2 = Pn[256], q3 = Pn[384];          \
    const unsigned short* hb = (HIN) + aoff;                                   \
    const bf16x8 A0 = *(const bf16x8*)(hb);                                    \
    const bf16x8 A1 = *(const bf16x8*)(hb + 32);                               \
    const bf16x8 A2 = *(const bf16x8*)(hb + 64);                               \
    const bf16x8 A3 = *(const bf16x8*)(hb + 96);                               \
    f32x4 a0 = {}, a1 = {}, a2 = {}, a3 = {};                                  \
    a0 = __builtin_amdgcn_mfma_f32_16x16x32_bf16(A0, Bfrag[0][0], a0, 0,0,0);  \
    a1 = __builtin_amdgcn_mfma_f32_16x16x32_bf16(A0, Bfrag[1][0], a1, 0,0,0);  \
    a2 = __builtin_amdgcn_mfma_f32_16x16x32_bf16(A0, Bfrag[2][0], a2, 0,0,0);  \
    a3 = __builtin_amdgcn_mfma_f32_16x16x32_bf16(A0, Bfrag[3][0], a3, 0,0,0);  \
    a0 = __builtin_amdgcn_mfma_f32_16x16x32_bf16(A1, Bfrag[0][1], a0, 0,0,0);  \
    a1 = __builtin_amdgcn_mfma_f32_16x16x32_bf16(A1, Bfrag[1][1], a1, 0,0,0);  \
    a2 = __builtin_amdgcn_mfma_f32_16x16x32_bf16(A1, Bfrag[2][1], a2, 0,0,0);  \
    a3 = __builtin_amdgcn_mfma_f32_16x16x32_bf16(A1, Bfrag[3][1], a3, 0,0,0);  \
    a0 = __builtin_amdgcn_mfma_f32_16x16x32_bf16(A2, Bfrag[0][2], a0, 0,0,0);  \
    a1 = __builtin_amdgcn_mfma_f32_16x16x32_bf16(A2, Bfrag[1][2], a1, 0,0,0);  \
    a2 = __builtin_amdgcn_mfma_f32_16x16x32_bf16(A2, Bfrag[2][2], a2, 0,0,0);  \
    a3 = __builtin_amdgcn_mfma_f32_16x16x32_bf16(A2, Bfrag[3][2], a3, 0,0,0);  \
    a0 = __builtin_amdgcn_mfma_f32_16x16x32_bf16(A3, Bfrag[0][3], a0, 0,0,0);  \
    a1 = __builtin_amdgcn_mfma_f32_16x16x32_bf16(A3, Bfrag[1][3], a1, 0,0,0);  \
    a2 = __builtin_amdgcn_mfma_f32_16x16x32_bf16(A3, Bfrag[2][3], a2, 0,0,0);  \
    a3 = __builtin_amdgcn_mfma_f32_16x16x32_bf16(A3, Bfrag[3][3], a3, 0,0,0);  \
    const float gi = (kg & 2) ? ((kg & 1) ? a0[3] : a0[2])                     \
                              : ((kg & 1) ? a0[1] : a0[0]);                    \
    const float gf = (kg & 2) ? ((kg & 1) ? a1[3] : a1[2])                     \
                              : ((kg & 1) ? a1[1] : a1[0]);                    \
    const float gg = (kg & 2) ? ((kg & 1) ? a2[3] : a2[2])                     \
                              : ((kg & 1) ? a2[1] : a2[0]);                    \
    const float go = (kg & 2) ? ((kg & 1) ? a3[3] : a3[2])                     \
                              : ((kg & 1) ? a3[1] : a3[0]);                    \
    const float iv = __builtin_amdgcn_rcpf(1.f + GEXP(-(gi + p0)));            \
    const float fv = __builtin_amdgcn_rcpf(1.f + GEXP(-(gf + p1)));            \
    const float gv = 1.f - 2.f * __builtin_amdgcn_rcpf(GEXP(gg + p2) + 1.f);   \
    const float ov = __builtin_amdgcn_rcpf(1.f + GEXP(-(go + p3)));            \
    cstate = fv * cstate + iv * gv;                                            \
    const float th =                                                           \
        1.f - 2.f * __builtin_amdgcn_rcpf(GEXP(cstate * SCALE_G) + 1.f);       \
    hv = ov * th;                                                              \
    (HOUT)[row * HSTRIDE + jfull] = f2bf(hv);                                  \
    p0 = q0; p1 = q1; p2 = q2; p3 = q3;                                        \
    __syncthreads();                                                           \
  }

  #pragma unroll 1
  for (int t = 0; t < SEQ; t += 2) {
    STEP(hbufA, hbufB, t)
    STEP(hbufB, hbufA, t + 1)
  }
#undef STEP

  // final h written once
  h_last[row][jfull] = hv;
  __syncthreads();

  // classifier: 4 rows x 256 vocab = 1024 outputs, 2 per thread
  const int erow = tid >> 7;          // 0..3
  const int ej   = tid & 127;
  #pragma unroll
  for (int half = 0; half < 2; ++half) {
    const int v = ej + half * 128;
    float acc = b_cls[v];
    const float4* w  = (const float4*)(W_cls + v * HID);
    const float4* hh = (const float4*)&h_last[erow][0];
    #pragma unroll
    for (int k = 0; k < HID / 4; ++k) {
      const float4 wv = w[k];
      const float4 hv4 = hh[k];
      acc += wv.x * hv4.x + wv.y * hv4.y + wv.z * hv4.z + wv.w * hv4.w;
    }
    out[(b0 + erow) * VOCAB + v] = acc;
  }
}

extern "C" void kernel_launch(void* const* d_in, const int* in_sizes, int n_in,
                              void* d_out, int out_size, void* d_ws, size_t ws_size,
                              hipStream_t stream) {
  const int*   inputs = (const int*)d_in[0];
  const float* emb    = (const float*)d_in[1];
  const float* W_ih   = (const float*)d_in[2];
  const float* W_hh   = (const float*)d_in[3];
  const float* b_ih   = (const float*)d_in[4];
  const float* b_hh   = (const float*)d_in[5];
  const float* W_cls  = (const float*)d_in[6];
  const float* b_cls  = (const float*)d_in[7];
  float* outp = (float*)d_out;

  float* Ptab = (float*)d_ws;

  prep_kernel<<<VOCAB, 256, 0, stream>>>(emb, W_ih, b_ih, b_hh, Ptab);
  lstm_kernel<<<BATCH / 4, 512, 0, stream>>>(inputs, Ptab, W_hh, W_cls, b_cls, outp);
}